// Round 5
// baseline (3105.963 us; speedup 1.0000x reference)
//
#include <hip/hip_runtime.h>
#include <cstddef>

#define T_STEPS 512
#define BATCH   64
#define EDIM    512
#define HDIM    512
#define ODIM    512
#define HALF    256

#define WLDS_ELEMS (16 * 5 * 64 * 8)            // 40960 elems = 80 KB
#define HB_ELEMS   (16 * HALF)                  // 4096 elems  = 8 KB
#define SMEM_BYTES ((WLDS_ELEMS + 2 * HB_ELEMS) * 2)   // 98304 B

typedef __bf16 bf16;
typedef __bf16 bf16x4 __attribute__((ext_vector_type(4)));
typedef __bf16 bf16x8 __attribute__((ext_vector_type(8)));
typedef float  f32x4  __attribute__((ext_vector_type(4)));

// ---------------------------------------------------------------------------
// MFMA GEMM (proven r0-r4): C[r,n] = sum_k X[r,k] * W[n, kw0+k] + bias[n]
// 128x128 tile, BK=32, 4 waves. REMAP (proven): rows b*T+t -> t*B+b.
// ---------------------------------------------------------------------------
template <typename XT, bool REMAP>
__global__ __launch_bounds__(256) void gemm_mfma_kernel(
    const XT* __restrict__ X, int ldx,
    const float* __restrict__ W, int ldw, int kw0,
    const float* __restrict__ bias,
    float* __restrict__ C, int ldc, int K)
{
  __shared__ __align__(16) bf16 Asm[8 * 64 * 8];
  __shared__ __align__(16) bf16 Bsm[8 * 64 * 8];

  const int tid  = threadIdx.x;
  const int row0 = blockIdx.x * 128;
  const int col0 = blockIdx.y * 128;
  const int w    = tid >> 6, lane = tid & 63;
  const int q    = lane >> 4, nl = lane & 15;
  const int wm   = w >> 1, wn = w & 1;

  f32x4 acc[4][4] = {};

  for (int k0 = 0; k0 < K; k0 += 32) {
#pragma unroll
    for (int rep = 0; rep < 2; ++rep) {
      int idx = tid + rep * 256;
      int mt = idx >> 6, l2 = idx & 63;
      const XT* src = X + (size_t)(row0 + mt * 16 + (l2 & 15)) * ldx
                        + k0 + (l2 >> 4) * 8;
      bf16x8 v;
#pragma unroll
      for (int u = 0; u < 8; ++u) v[u] = (bf16)(float)src[u];
      *(bf16x8*)&Asm[(size_t)idx * 8] = v;
    }
#pragma unroll
    for (int rep = 0; rep < 2; ++rep) {
      int idx = tid + rep * 256;
      int nt = idx >> 6, l2 = idx & 63;
      const float* src = W + (size_t)(col0 + nt * 16 + (l2 & 15)) * ldw
                           + kw0 + k0 + (l2 >> 4) * 8;
      bf16x8 v;
#pragma unroll
      for (int u = 0; u < 8; ++u) v[u] = (bf16)src[u];
      *(bf16x8*)&Bsm[(size_t)idx * 8] = v;
    }
    __syncthreads();

    bf16x8 a[4], b[4];
#pragma unroll
    for (int i = 0; i < 4; ++i)
      a[i] = *(bf16x8*)&Asm[(size_t)((wm * 4 + i) * 64 + lane) * 8];
#pragma unroll
    for (int j = 0; j < 4; ++j)
      b[j] = *(bf16x8*)&Bsm[(size_t)((wn * 4 + j) * 64 + lane) * 8];
#pragma unroll
    for (int i = 0; i < 4; ++i)
#pragma unroll
      for (int j = 0; j < 4; ++j)
        acc[i][j] = __builtin_amdgcn_mfma_f32_16x16x32_bf16(a[i], b[j], acc[i][j], 0, 0, 0);
    __syncthreads();
  }

#pragma unroll
  for (int i = 0; i < 4; ++i)
#pragma unroll
    for (int j = 0; j < 4; ++j) {
      int colg = col0 + wn * 64 + j * 16 + nl;
#pragma unroll
      for (int r = 0; r < 4; ++r) {
        size_t rowg = (size_t)(row0 + wm * 64 + i * 16 + q * 4 + r);
        size_t crow = REMAP ? (((rowg & (T_STEPS - 1)) << 6) | (rowg >> 9)) : rowg;
        C[crow * ldc + colg] = acc[i][j][r] + bias[colg];
      }
    }
}

// ---------------------------------------------------------------------------
// Paired scan, round-5: 8 active blocks = 2 per cluster (16 batch rows),
// each owning 256 hidden cols. Fixes of r1's fatal exchange:
//   - exchange data via 8B AGENT-scope ATOMIC stores into dedicated 8KB
//     ping-pong buffers (fixed addresses -> L3-resident, placement-agnostic
//     coherence; NO __threadfence / L2 writeback anywhere in the loop)
//   - flag published AFTER __syncthreads (drains vmcnt => exchange stores
//     complete at the coherence point before the flag is visible)
//   - poll + 16x8B peer loads issued at step TOP; acc-init + A-prefetch +
//     own-half MFMA (~900 cyc) cover the L3 latency
// Per block: 8 waves x 2 n-tiles; Wreg[2][11] = 176 regs (ktg 5..15),
// Wlds ktg 0..4 (80 KB); own-h double-buffered in LDS (2x8KB, XOR-swizzled,
// r3-proven). 256-reg budget honored (r4 lesson): 176+8+8+32 transient.
// Flag protocol: flag_s = #completed steps. At step t: wait flag_peer >= t
// (peer h_{t-1} available in buf[(t-1)&1]; also proves peer consumed my
// h_{t-2} from buf[t&1] => WAR-safe overwrite). Proven r1-fallback family.
// ---------------------------------------------------------------------------
template <int S>
__device__ __forceinline__ void scan_half(
    const float* __restrict__ A,     // [T, B, H] fp32
    const float* __restrict__ W1,    // [H, E+H] fp32
    bf16* __restrict__ Hbf,          // [B, T, H] bf16
    int* myflag, int* paflag,
    bf16* __restrict__ mybuf,        // my exch ping-pong: 2 x HB_ELEMS
    const bf16* __restrict__ pbuf,   // peer exch ping-pong
    bf16* Wlds, bf16* h0, bf16* h1, int rb0)
{
  const int tid  = threadIdx.x;
  const int w    = tid >> 6, lane = tid & 63;
  const int q    = lane >> 4, nl = lane & 15;
  const int col0 = S * HALF;
  const int sw   = (nl & 7) << 3;
  const int tg0  = w * 2;

  // ---- one-time: W ktg 0..4 for this block's 16 n-tiles -> LDS -----------
  for (int idx = tid; idx < 16 * 5 * 64; idx += 512) {
    int l  = idx & 63;
    int kt = (idx >> 6) % 5;
    int tg = (idx >> 6) / 5;
    int n  = col0 + tg * 16 + (l & 15);
    int k  = kt * 32 + (l >> 4) * 8;
    const float* src = W1 + (size_t)n * (EDIM + HDIM) + EDIM + k;
    bf16x8 v;
#pragma unroll
    for (int u = 0; u < 8; ++u) v[u] = (bf16)src[u];
    *(bf16x8*)&Wlds[(size_t)idx * 8] = v;
  }

  // ---- one-time: W ktg 5..15 for this wave's 2 tiles -> 176 VGPRs --------
  bf16x8 Wreg[2][11];
#pragma unroll
  for (int i = 0; i < 2; ++i) {
    const float* wrow = W1 + (size_t)(col0 + w * 32 + i * 16 + nl) * (EDIM + HDIM)
                        + EDIM + q * 8;
#pragma unroll
    for (int j = 0; j < 11; ++j) {
      const float* src = wrow + (j + 5) * 32;
      bf16x8 v;
#pragma unroll
      for (int u = 0; u < 8; ++u) v[u] = (bf16)src[u];
      Wreg[i][j] = v;
    }
  }
  __syncthreads();

  // ---- prefetch A_0 ------------------------------------------------------
  f32x4 An[2];
  {
    const float* ap = A + (size_t)(rb0 + nl) * HDIM + col0 + w * 32 + q * 4;
    An[0] = *(const f32x4*)ap;
    An[1] = *(const f32x4*)(ap + 16);
  }

  f32x4 acc[2];
  union PU { unsigned long long u[2]; bf16x8 v; };
  union HB { bf16x4 v; unsigned long long u; };

  for (int t = 0; t < T_STEPS; ++t) {
    bf16* hr = (t & 1) ? h1 : h0;
    bf16* hw = (t & 1) ? h0 : h1;

    // ---- poll peer; issue 16x8B peer-half loads (L3, latency-covered) ----
    unsigned long long pl0[8], pl1[8];
    if (t > 0) {
      for (;;) {
        int v = __hip_atomic_load(paflag, __ATOMIC_RELAXED,
                                  __HIP_MEMORY_SCOPE_AGENT);
        if (v >= t) break;
        __builtin_amdgcn_s_sleep(1);
      }
      const bf16* pb = pbuf + ((t - 1) & 1) * HB_ELEMS;
      unsigned long long* pr = (unsigned long long*)(pb + nl * HALF + q * 8);
#pragma unroll
      for (int j = 0; j < 8; ++j) {
        pl0[j] = __hip_atomic_load(pr + j * 8,     __ATOMIC_RELAXED,
                                   __HIP_MEMORY_SCOPE_AGENT);
        pl1[j] = __hip_atomic_load(pr + j * 8 + 1, __ATOMIC_RELAXED,
                                   __HIP_MEMORY_SCOPE_AGENT);
      }
    }

    // ---- acc init + A_{t+1} prefetch -------------------------------------
    acc[0] = An[0];
    acc[1] = An[1];
    {
      int tn = (t + 1 < T_STEPS) ? t + 1 : 0;
      const float* ap = A + ((size_t)tn * BATCH + rb0 + nl) * HDIM
                        + col0 + w * 32 + q * 4;
      An[0] = *(const f32x4*)ap;
      An[1] = *(const f32x4*)(ap + 16);
    }

    if (t > 0) {
      // ---- own-half K (af from LDS; covers peer-load latency) ------------
#pragma unroll
      for (int j = 0; j < 8; ++j) {
        bf16x8 af = *(bf16x8*)&hr[nl * HALF + ((j * 32 + q * 8) ^ sw)];
        const int ktg = S * 8 + j;
#pragma unroll
        for (int i = 0; i < 2; ++i) {
          bf16x8 wb;
          if (ktg < 5)
            wb = *(bf16x8*)&Wlds[(size_t)(((tg0 + i) * 5 + ktg) * 64 + lane) * 8];
          else
            wb = Wreg[i][ktg - 5];
          acc[i] = __builtin_amdgcn_mfma_f32_16x16x32_bf16(wb, af, acc[i], 0, 0, 0);
        }
      }
      // ---- peer-half K (af from in-flight L3 regs) -----------------------
#pragma unroll
      for (int j = 0; j < 8; ++j) {
        PU pu; pu.u[0] = pl0[j]; pu.u[1] = pl1[j];
        const int ktg = (1 - S) * 8 + j;
#pragma unroll
        for (int i = 0; i < 2; ++i) {
          bf16x8 wb;
          if (ktg < 5)
            wb = *(bf16x8*)&Wlds[(size_t)(((tg0 + i) * 5 + ktg) * 64 + lane) * 8];
          else
            wb = Wreg[i][ktg - 5];
          acc[i] = __builtin_amdgcn_mfma_f32_16x16x32_bf16(wb, pu.v, acc[i], 0, 0, 0);
        }
      }
    }

    // ---- relu; write h_t: LDS (swizzled) + exch (atomic 8B) + Hbf --------
    {
      bf16* mb = mybuf + (t & 1) * HB_ELEMS;
#pragma unroll
      for (int i = 0; i < 2; ++i) {
        bf16x4 hv;
#pragma unroll
        for (int r = 0; r < 4; ++r)
          hv[r] = (bf16)fmaxf(acc[i][r], 0.0f);
        int colL = w * 32 + i * 16 + q * 4;
        *(bf16x4*)&hw[nl * HALF + (colL ^ sw)] = hv;
        HB hb; hb.v = hv;
        __hip_atomic_store((unsigned long long*)(mb + nl * HALF + colL), hb.u,
                           __ATOMIC_RELAXED, __HIP_MEMORY_SCOPE_AGENT);
        *(bf16x4*)(Hbf + ((size_t)(rb0 + nl) * T_STEPS + t) * HDIM
                   + col0 + colL) = hv;
      }
    }

    __syncthreads();   // drains vmcnt+lgkm: exch stores complete, LDS visible
    if (tid == 0)
      __hip_atomic_store(myflag, t + 1, __ATOMIC_RELAXED,
                         __HIP_MEMORY_SCOPE_AGENT);
  }
}

__global__ __launch_bounds__(512, 2) void scan_pair_kernel(
    const float* __restrict__ A,
    const float* __restrict__ W1,
    bf16* __restrict__ Hbf,
    int* __restrict__ flags,
    bf16* __restrict__ exch)
{
  extern __shared__ __align__(16) bf16 smem[];
  bf16* Wlds = smem;
  bf16* h0   = smem + WLDS_ELEMS;
  bf16* h1   = h0 + HB_ELEMS;

  const int bid = blockIdx.x;
  int c, s;
  if (bid < 4)                   { c = bid;     s = 0; }
  else if (bid >= 8 && bid < 12) { c = bid - 8; s = 1; }
  else return;   // inert blocks: grid=16 so pairs (c, c+8) likely share an XCD

  int* myflag = flags + (c * 2 + s) * 32;
  int* paflag = flags + (c * 2 + (1 - s)) * 32;
  bf16* mybuf = exch + (size_t)((c * 2 + s) * 2) * HB_ELEMS;
  bf16* pbuf  = exch + (size_t)((c * 2 + (1 - s)) * 2) * HB_ELEMS;

  if (s == 0)
    scan_half<0>(A, W1, Hbf, myflag, paflag, mybuf, pbuf, Wlds, h0, h1, c * 16);
  else
    scan_half<1>(A, W1, Hbf, myflag, paflag, mybuf, pbuf, Wlds, h0, h1, c * 16);
}

// ---------------------------------------------------------------------------
__global__ __launch_bounds__(256) void copy_hfinal_kernel(
    const bf16* __restrict__ Hbf, float* __restrict__ out)
{
  int i = blockIdx.x * blockDim.x + threadIdx.x;
  int b = i / HDIM, n = i % HDIM;
  out[i] = (float)Hbf[((size_t)b * T_STEPS + (T_STEPS - 1)) * HDIM + n];
}

extern "C" void kernel_launch(void* const* d_in, const int* in_sizes, int n_in,
                              void* d_out, int out_size, void* d_ws, size_t ws_size,
                              hipStream_t stream) {
  const float* x  = (const float*)d_in[0];
  const float* W1 = (const float*)d_in[1];
  const float* b1 = (const float*)d_in[2];
  const float* W2 = (const float*)d_in[3];
  const float* b2 = (const float*)d_in[4];

  float* out = (float*)d_out;
  float* A   = out;   // fp32 x-projection staged in d_out ([T,B,H] order);
                      // consumed by the scan before GEMM3 overwrites it

  bf16* Hbf  = (bf16*)d_ws;                                    // 32 MB
  char* tail = (char*)d_ws + (size_t)BATCH * T_STEPS * HDIM * 2;
  int*  flags = (int*)tail;                                    // 1 KB (pad 4 KB)
  bf16* exch  = (bf16*)(tail + 4096);                          // 128 KB

  hipMemsetAsync(flags, 0, 4096, stream);

  // 1) A = X @ W1[:, :E]^T + b1  (bf16 MFMA, fp32 out, rows remapped to [T,B])
  {
    dim3 grid(BATCH * T_STEPS / 128, HDIM / 128);
    gemm_mfma_kernel<float, true><<<grid, 256, 0, stream>>>(
        x, EDIM, W1, EDIM + HDIM, 0, b1, A, HDIM, EDIM);
  }

  // 2) paired scan: 8 active blocks, 98,304 B dynamic LDS each
  hipFuncSetAttribute(
      reinterpret_cast<const void*>(scan_pair_kernel),
      hipFuncAttributeMaxDynamicSharedMemorySize, SMEM_BYTES);
  scan_pair_kernel<<<16, 512, SMEM_BYTES, stream>>>(A, W1, Hbf, flags, exch);

  // 3) outs = Hbf @ W2^T + b2 (overwrites the A staging area)
  {
    dim3 grid(BATCH * T_STEPS / 128, ODIM / 128);
    gemm_mfma_kernel<bf16, false><<<grid, 256, 0, stream>>>(
        Hbf, HDIM, W2, HDIM, 0, b2, out, ODIM, HDIM);
  }

  // 4) h_final tail
  copy_hfinal_kernel<<<(BATCH * HDIM) / 256, 256, 0, stream>>>(
      Hbf, out + (size_t)BATCH * T_STEPS * ODIM);
}

// Round 6
// 1375.811 us; speedup vs baseline: 2.2576x; 2.2576x over previous
//
#include <hip/hip_runtime.h>
#include <cstddef>
#include <type_traits>

#define T_STEPS 512
#define BATCH   64
#define EDIM    512
#define HDIM    512
#define ODIM    512

#define W_ELEMS  (32 * 4 * 64 * 8)  // W kt 0..3: 65536 elems = 131072 B
#define HB_ELEMS (16 * 512)         // one h buffer: 8192 elems = 16384 B

typedef __bf16 bf16;
typedef __bf16 bf16x4 __attribute__((ext_vector_type(4)));
typedef __bf16 bf16x8 __attribute__((ext_vector_type(8)));
typedef float  f32x4  __attribute__((ext_vector_type(4)));

// LDS-only barrier: does NOT drain vmcnt, so in-flight global loads/stores
// (A prefetch, Hbf stores) ride across it. rule-18 fence: sched_barrier after.
__device__ __forceinline__ void barrier_lds() {
  asm volatile("s_waitcnt lgkmcnt(0)\n\ts_barrier" ::: "memory");
  __builtin_amdgcn_sched_barrier(0);
}

// ---------------------------------------------------------------------------
// MFMA GEMM, round-6 staging rewrite: C[r,n] = sum_k X[r,k]*W[n,kw0+k] + b[n]
// 128x128 tile, BK=32, 4 waves. Frag layouts and epilogue byte-identical to
// the r0-r5 proven kernel; ONLY the global->LDS staging changed:
//   old: 8 scalar loads/thread from 16 scattered rows (non-coalesced)
//   new: thread (rep, tid) handles row_local=(tid>>2)+rep*64, c0=(tid&3)*8:
//        loads 8 CONSECUTIVE K-elems (2x f32x4, or 1x bf16x8 when XT=bf16),
//        converts, writes one ds_write_b128 at the same frag-layout address
//        (mt*64 + q*16 + nl)*8, q=c0/8, nl=row_local&15, mt=row_local>>4.
//   4-thread groups cover 128 B contiguous per row -> coalesced.
// REMAP (proven): rows b*T+t -> t*B+b  ([B,T,*] -> [T,B,*]).
// ---------------------------------------------------------------------------
template <typename XT, bool REMAP>
__global__ __launch_bounds__(256) void gemm_mfma_kernel(
    const XT* __restrict__ X, int ldx,
    const float* __restrict__ W, int ldw, int kw0,
    const float* __restrict__ bias,
    float* __restrict__ C, int ldc, int K)
{
  __shared__ __align__(16) bf16 Asm[8 * 64 * 8];
  __shared__ __align__(16) bf16 Bsm[8 * 64 * 8];

  const int tid  = threadIdx.x;
  const int row0 = blockIdx.x * 128;
  const int col0 = blockIdx.y * 128;
  const int w    = tid >> 6, lane = tid & 63;
  const int q    = lane >> 4, nl = lane & 15;
  const int wm   = w >> 1, wn = w & 1;

  // staging coords (computed once)
  const int srow = tid >> 2;        // 0..63, + rep*64
  const int sq   = tid & 3;         // k-chunk: c0 = sq*8
  f32x4 acc[4][4] = {};

  for (int k0 = 0; k0 < K; k0 += 32) {
#pragma unroll
    for (int rep = 0; rep < 2; ++rep) {
      int rl = srow + rep * 64;                 // row_local 0..127
      int mt = rl >> 4, snl = rl & 15;
      bf16x8 v;
      const XT* src = X + (size_t)(row0 + rl) * ldx + k0 + sq * 8;
      if constexpr (std::is_same_v<XT, float>) {
        f32x4 a0 = *(const f32x4*)src;
        f32x4 a1 = *(const f32x4*)(src + 4);
#pragma unroll
        for (int u = 0; u < 4; ++u) { v[u] = (bf16)a0[u]; v[u + 4] = (bf16)a1[u]; }
      } else {
        v = *(const bf16x8*)src;
      }
      *(bf16x8*)&Asm[(size_t)((mt * 4 + sq) * 16 + snl) * 8] = v;
    }
#pragma unroll
    for (int rep = 0; rep < 2; ++rep) {
      int rl = srow + rep * 64;
      int nt = rl >> 4, snl = rl & 15;
      const float* src = W + (size_t)(col0 + rl) * ldw + kw0 + k0 + sq * 8;
      f32x4 b0 = *(const f32x4*)src;
      f32x4 b1 = *(const f32x4*)(src + 4);
      bf16x8 v;
#pragma unroll
      for (int u = 0; u < 4; ++u) { v[u] = (bf16)b0[u]; v[u + 4] = (bf16)b1[u]; }
      *(bf16x8*)&Bsm[(size_t)((nt * 4 + sq) * 16 + snl) * 8] = v;
    }
    __syncthreads();

    bf16x8 a[4], b[4];
#pragma unroll
    for (int i = 0; i < 4; ++i)
      a[i] = *(bf16x8*)&Asm[(size_t)((wm * 4 + i) * 64 + lane) * 8];
#pragma unroll
    for (int j = 0; j < 4; ++j)
      b[j] = *(bf16x8*)&Bsm[(size_t)((wn * 4 + j) * 64 + lane) * 8];
#pragma unroll
    for (int i = 0; i < 4; ++i)
#pragma unroll
      for (int j = 0; j < 4; ++j)
        acc[i][j] = __builtin_amdgcn_mfma_f32_16x16x32_bf16(a[i], b[j], acc[i][j], 0, 0, 0);
    __syncthreads();
  }

#pragma unroll
  for (int i = 0; i < 4; ++i)
#pragma unroll
    for (int j = 0; j < 4; ++j) {
      int colg = col0 + wn * 64 + j * 16 + nl;
#pragma unroll
      for (int r = 0; r < 4; ++r) {
        size_t rowg = (size_t)(row0 + wm * 64 + i * 16 + q * 4 + r);
        size_t crow = REMAP ? (((rowg & (T_STEPS - 1)) << 6) | (rowg >> 9)) : rowg;
        C[crow * ldc + colg] = acc[i][j][r] + bias[colg];
      }
    }
}

// ---------------------------------------------------------------------------
// Scan (r3 verbatim, proven 1174 us / passing): 4 WGs x 512 threads (8 waves),
// recurrence closes in-block; r1/r5 proved cross-block exchange is fatal.
// Operand-swapped MFMA, XOR-swizzled double-buffered h, one LDS-only
// barrier/step, W kt0..3 in LDS + kt4..15 in 192 VGPRs (capacity-exact).
// ---------------------------------------------------------------------------
template <int DBUF>
__global__ __launch_bounds__(512, 2) void scan_kernel(
    const float* __restrict__ A,     // [T, B, H] fp32 (t-major, REMAP GEMM)
    const float* __restrict__ W1,    // [H, E+H] fp32
    bf16* __restrict__ Hbf)          // [B, T, H] bf16
{
  extern __shared__ __align__(16) bf16 smem[];
  bf16* Wlds = smem;                       // [tg(32)][kt(4)][lane(64)][8]
  bf16* hb0  = smem + W_ELEMS;             // [16][512] swizzled
  bf16* hb1  = DBUF ? (hb0 + HB_ELEMS) : hb0;

  const int tid  = threadIdx.x;
  const int c    = blockIdx.x;
  const int w    = tid >> 6, lane = tid & 63;
  const int q    = lane >> 4, nl = lane & 15;
  const int rb0  = c * 16;
  const int n0   = w * 64;
  const int sw   = (nl & 7) << 3;          // elem-granularity row swizzle

  // ---- one-time: W kt 0..3, all 32 n-tiles -> LDS ------------------------
  for (int idx = tid; idx < 32 * 4 * 64; idx += 512) {
    int l  = idx & 63;
    int kt = (idx >> 6) & 3;
    int tg = idx >> 8;
    int n  = tg * 16 + (l & 15);
    int k  = kt * 32 + (l >> 4) * 8;
    const float* src = W1 + (size_t)n * (EDIM + HDIM) + EDIM + k;
    bf16x8 v;
#pragma unroll
    for (int u = 0; u < 8; ++u) v[u] = (bf16)src[u];
    *(bf16x8*)&Wlds[(size_t)idx * 8] = v;
  }

  // ---- one-time: W kt 4..15 for this wave's 4 tiles -> 192 VGPRs ---------
  bf16x8 Wreg[4][12];
#pragma unroll
  for (int i = 0; i < 4; ++i) {
    int n = n0 + i * 16 + nl;
    const float* wrow = W1 + (size_t)n * (EDIM + HDIM) + EDIM;
#pragma unroll
    for (int kt2 = 0; kt2 < 12; ++kt2) {
      const float* src = wrow + (kt2 + 4) * 32 + q * 8;
      bf16x8 v;
#pragma unroll
      for (int u = 0; u < 8; ++u) v[u] = (bf16)src[u];
      Wreg[i][kt2] = v;
    }
  }
  __syncthreads();

  // ---- prefetch A_0 (4x f32x4; t-major A; proven mapping) ----------------
  f32x4 An[4];
  {
    const float* ap = A + (size_t)(rb0 + nl) * HDIM + n0 + q * 4;
    An[0] = *(const f32x4*)(ap);
    An[1] = *(const f32x4*)(ap + 16);
    An[2] = *(const f32x4*)(ap + 32);
    An[3] = *(const f32x4*)(ap + 48);
  }

  f32x4 acc[4];

  for (int t = 0; t < T_STEPS; ++t) {
    bf16* hr = (t & 1) ? hb1 : hb0;
    bf16* hw = (t & 1) ? hb0 : hb1;

    // ---- acc init from prefetched A_t; issue A_{t+1} prefetch ------------
#pragma unroll
    for (int i = 0; i < 4; ++i) acc[i] = An[i];
    {
      int tn = (t + 1 < T_STEPS) ? t + 1 : 0;
      const float* ap = A + ((size_t)tn * BATCH + rb0 + nl) * HDIM + n0 + q * 4;
      An[0] = *(const f32x4*)(ap);
      An[1] = *(const f32x4*)(ap + 16);
      An[2] = *(const f32x4*)(ap + 32);
      An[3] = *(const f32x4*)(ap + 48);
    }

    // ---- h_{t-1} @ W1h^T over K=512 (operand-swapped MFMA) ---------------
    if (t > 0) {
#pragma unroll
      for (int kt = 0; kt < 16; ++kt) {
        bf16x8 af = *(bf16x8*)&hr[nl * 512 + ((kt * 32 + q * 8) ^ sw)];
        if (kt < 4) {
#pragma unroll
          for (int i = 0; i < 4; ++i) {
            bf16x8 wb = *(bf16x8*)&Wlds[(size_t)(((w * 4 + i) * 4 + kt) * 64 + lane) * 8];
            acc[i] = __builtin_amdgcn_mfma_f32_16x16x32_bf16(wb, af, acc[i], 0, 0, 0);
          }
        } else {
#pragma unroll
          for (int i = 0; i < 4; ++i)
            acc[i] = __builtin_amdgcn_mfma_f32_16x16x32_bf16(Wreg[i][kt - 4], af, acc[i], 0, 0, 0);
        }
      }
    }

    if (!DBUF) barrier_lds();   // single-buffer WAR: reads done before overwrite

    // ---- relu; write h_t to hw (swizzled) + Hbf directly from regs -------
#pragma unroll
    for (int i = 0; i < 4; ++i) {
      bf16x4 hv;
#pragma unroll
      for (int r = 0; r < 4; ++r) {
        float v = acc[i][r] > 0.0f ? acc[i][r] : 0.0f;
        hv[r] = (bf16)v;
      }
      *(bf16x4*)&hw[nl * 512 + ((n0 + i * 16 + q * 4) ^ sw)] = hv;
      *(bf16x4*)(Hbf + ((size_t)(rb0 + nl) * T_STEPS + t) * HDIM
                 + n0 + i * 16 + q * 4) = hv;
    }

    barrier_lds();   // h_t visible; orders reads-of-hr vs next-step writes
  }
}

// ---------------------------------------------------------------------------
__global__ __launch_bounds__(256) void copy_hfinal_kernel(
    const bf16* __restrict__ Hbf, float* __restrict__ out)
{
  int i = blockIdx.x * blockDim.x + threadIdx.x;
  int b = i / HDIM, n = i % HDIM;
  out[i] = (float)Hbf[((size_t)b * T_STEPS + (T_STEPS - 1)) * HDIM + n];
}

extern "C" void kernel_launch(void* const* d_in, const int* in_sizes, int n_in,
                              void* d_out, int out_size, void* d_ws, size_t ws_size,
                              hipStream_t stream) {
  const float* x  = (const float*)d_in[0];
  const float* W1 = (const float*)d_in[1];
  const float* b1 = (const float*)d_in[2];
  const float* W2 = (const float*)d_in[3];
  const float* b2 = (const float*)d_in[4];

  float* out = (float*)d_out;
  float* A   = out;   // fp32 x-projection staged in d_out ([T,B,H] order);
                      // consumed by the scan before GEMM3 overwrites it

  bf16* Hbf  = (bf16*)d_ws;   // 32 MB

  // 1) A = X @ W1[:, :E]^T + b1  (bf16 MFMA, fp32 out, rows remapped to [T,B])
  {
    dim3 grid(BATCH * T_STEPS / 128, HDIM / 128);
    gemm_mfma_kernel<float, true><<<grid, 256, 0, stream>>>(
        x, EDIM, W1, EDIM + HDIM, 0, b1, A, HDIM, EDIM);
  }

  // 2) scan (r3 proven). DBUF = 163840 B dynamic LDS (exactly 160 KiB);
  // deterministic fallback to the single-buffer variant.
  {
    int smem_dbuf = (W_ELEMS + 2 * HB_ELEMS) * 2;   // 163840
    int smem_sbuf = (W_ELEMS + 1 * HB_ELEMS) * 2;   // 147456
    hipError_t e = hipFuncSetAttribute(
        reinterpret_cast<const void*>(scan_kernel<1>),
        hipFuncAttributeMaxDynamicSharedMemorySize, smem_dbuf);
    if (e == hipSuccess) {
      scan_kernel<1><<<4, 512, smem_dbuf, stream>>>(A, W1, Hbf);
    } else {
      hipFuncSetAttribute(
          reinterpret_cast<const void*>(scan_kernel<0>),
          hipFuncAttributeMaxDynamicSharedMemorySize, smem_sbuf);
      scan_kernel<0><<<4, 512, smem_sbuf, stream>>>(A, W1, Hbf);
    }
  }

  // 3) outs = Hbf @ W2^T + b2 (overwrites the A staging area)
  {
    dim3 grid(BATCH * T_STEPS / 128, ODIM / 128);
    gemm_mfma_kernel<bf16, false><<<grid, 256, 0, stream>>>(
        Hbf, HDIM, W2, HDIM, 0, b2, out, ODIM, HDIM);
  }

  // 4) h_final tail
  copy_hfinal_kernel<<<(BATCH * HDIM) / 256, 256, 0, stream>>>(
      Hbf, out + (size_t)BATCH * T_STEPS * ODIM);
}